// Round 1
// baseline (166.708 us; speedup 1.0000x reference)
//
#include <hip/hip_runtime.h>
#include <hip/hip_bf16.h>
#include <math.h>

#define SELU_SCALE 1.0507009873554805f
#define SELU_ALPHA 1.6732632423543772f

static constexpr int B_ = 16, T_ = 16, L_ = 512, H_ = 768;

typedef __bf16 bf16x8 __attribute__((ext_vector_type(8)));
typedef float  f32x4  __attribute__((ext_vector_type(4)));

__device__ __forceinline__ float bf_lo(unsigned u) { return __uint_as_float(u << 16); }
__device__ __forceinline__ float bf_hi(unsigned u) { return __uint_as_float(u & 0xFFFF0000u); }

__device__ __forceinline__ float selu_core(float x) {
    float e = fmaf(__expf(x), SELU_ALPHA, -SELU_ALPHA);
    return x > 0.0f ? x : e;
}

// LDS k-segment slot swizzle: slot = seg ^ ((row>>1)&3). r6 measured 0 conflicts
// for these write/read patterns (16-row x 64B contiguous 1KB per wave-op).
__device__ __forceinline__ int xsw(int r) { return (r >> 1) & 3; }

__device__ __forceinline__ bf16x8 pack8(float4 a, float4 b) {
    bf16x8 o;
    o[0] = (__bf16)a.x; o[1] = (__bf16)a.y; o[2] = (__bf16)a.z; o[3] = (__bf16)a.w;
    o[4] = (__bf16)b.x; o[5] = (__bf16)b.y; o[6] = (__bf16)b.z; o[7] = (__bf16)b.w;
    return o;
}

// ---------------- fused NT GEMM (WE + WD), no prep pass -------------------------
// Unchanged structure from the 152µs session kernel, except the WD path now
// writes f32 (wdf) so scores_k needs no per-use unpack of wd. 128x128 tile,
// 4 waves of 64x64 (4x4 MFMA 16x16x32), BK=32, prefetch distance ~2, statically
// named X/Y register sets, XCD-aware block mapping.
__global__ __launch_bounds__(256, 2) void gemm_k(
        const float* __restrict__ hn, const float* __restrict__ dec,
        const float* __restrict__ w1, const float* __restrict__ w2,
        const int* __restrict__ Yi,
        __bf16* __restrict__ web, float* __restrict__ wdf,
        float* __restrict__ out) {
    __shared__ __bf16 As[128 * 32];   // 8 KB
    __shared__ __bf16 Bs[128 * 32];   // 8 KB

    const int tid = threadIdx.x;
    if (blockIdx.x == 0 && tid == 0) out[0] = 0.0f;   // for loss_k atomics

    int bx = blockIdx.x;
    const float* Wf; int m0, n0; bool wd;
    if (bx < 384) {                      // WE: 64 m-tiles x 6 n-chunks
        wd = false; Wf = w1;
        m0 = (bx & 63) * 128; n0 = (bx >> 6) * 128;
    } else {                             // WD: 2 m-tiles x 6 n-chunks
        wd = true; bx -= 384; Wf = w2;
        m0 = (bx & 1) * 128;  n0 = (bx >> 1) * 128;
    }

    const int wave = tid >> 6, lane = tid & 63;
    const int wm = (wave >> 1) * 64, wn = (wave & 1) * 64;
    const int lr = lane & 15, q = lane >> 4;

    // staging: thread -> rows r1 = wave*32+(lane>>2), r2 = r1+16; slot s3 = lane&3
    // holds global k-seg g1 = s3 ^ xsw(r1)  (xsw(r1) == xsw(r1+16))
    const int r1 = wave * 32 + (lane >> 2);
    const int s3 = lane & 3;
    const int g1 = s3 ^ xsw(r1);

    const float *aG1, *aG2;
    if (!wd) {
        aG1 = hn + (size_t)(m0 + r1) * 768 + g1 * 8;
        aG2 = aG1 + (size_t)16 * 768;
    } else {
        int bt1 = m0 + r1, bt2 = bt1 + 16;
        aG1 = dec + ((size_t)((bt1 >> 4) * L_ + Yi[bt1])) * 768 + g1 * 8;
        aG2 = dec + ((size_t)((bt2 >> 4) * L_ + Yi[bt2])) * 768 + g1 * 8;
    }
    const float* bG1 = Wf + (size_t)(n0 + r1) * 768 + g1 * 8;
    const float* bG2 = bG1 + (size_t)16 * 768;

    bf16x8* AsW1 = (bf16x8*)&As[r1 * 32 + s3 * 8];
    bf16x8* AsW2 = (bf16x8*)&As[(r1 + 16) * 32 + s3 * 8];
    bf16x8* BsW1 = (bf16x8*)&Bs[r1 * 32 + s3 * 8];
    bf16x8* BsW2 = (bf16x8*)&Bs[(r1 + 16) * 32 + s3 * 8];

    // fragment read offsets (global seg q at slot q^xsw(row))
    int aoff[4], boff[4];
#pragma unroll
    for (int i = 0; i < 4; ++i) {
        int r = wm + i * 16 + lr;
        aoff[i] = r * 32 + (q ^ xsw(r)) * 8;
    }
#pragma unroll
    for (int j = 0; j < 4; ++j) {
        int r = wn + j * 16 + lr;
        boff[j] = r * 32 + (q ^ xsw(r)) * 8;
    }

    f32x4 acc[4][4] = {};

    // prologue: tile k=0 -> set X, tile k=32 -> set Y (statically named)
    float4 xa1a = *(const float4*)(aG1);      float4 xa1b = *(const float4*)(aG1 + 4);
    float4 xa2a = *(const float4*)(aG2);      float4 xa2b = *(const float4*)(aG2 + 4);
    float4 xb1a = *(const float4*)(bG1);      float4 xb1b = *(const float4*)(bG1 + 4);
    float4 xb2a = *(const float4*)(bG2);      float4 xb2b = *(const float4*)(bG2 + 4);
    float4 ya1a = *(const float4*)(aG1 + 32); float4 ya1b = *(const float4*)(aG1 + 36);
    float4 ya2a = *(const float4*)(aG2 + 32); float4 ya2b = *(const float4*)(aG2 + 36);
    float4 yb1a = *(const float4*)(bG1 + 32); float4 yb1b = *(const float4*)(bG1 + 36);
    float4 yb2a = *(const float4*)(bG2 + 32); float4 yb2b = *(const float4*)(bG2 + 36);

#pragma unroll 1
    for (int k0 = 0; k0 < 768; k0 += 64) {
        // ======== sub-iter X: tile k0 ========
        {
            *AsW1 = pack8(xa1a, xa1b);
            *AsW2 = pack8(xa2a, xa2b);
            *BsW1 = pack8(xb1a, xb1b);
            *BsW2 = pack8(xb2a, xb2b);
            asm volatile("s_waitcnt lgkmcnt(0)\n\ts_barrier" ::: "memory");
            if (k0 + 64 < 768) {
                xa1a = *(const float4*)(aG1 + k0 + 64); xa1b = *(const float4*)(aG1 + k0 + 68);
                xa2a = *(const float4*)(aG2 + k0 + 64); xa2b = *(const float4*)(aG2 + k0 + 68);
                xb1a = *(const float4*)(bG1 + k0 + 64); xb1b = *(const float4*)(bG1 + k0 + 68);
                xb2a = *(const float4*)(bG2 + k0 + 64); xb2b = *(const float4*)(bG2 + k0 + 68);
            }
            bf16x8 af[4], bfr[4];
#pragma unroll
            for (int i = 0; i < 4; ++i) af[i]  = *(const bf16x8*)&As[aoff[i]];
#pragma unroll
            for (int j = 0; j < 4; ++j) bfr[j] = *(const bf16x8*)&Bs[boff[j]];
#pragma unroll
            for (int i = 0; i < 4; ++i)
#pragma unroll
                for (int j = 0; j < 4; ++j)
                    acc[i][j] = __builtin_amdgcn_mfma_f32_16x16x32_bf16(af[i], bfr[j], acc[i][j], 0, 0, 0);
            asm volatile("s_barrier" ::: "memory");
        }
        // ======== sub-iter Y: tile k0+32 ========
        {
            *AsW1 = pack8(ya1a, ya1b);
            *AsW2 = pack8(ya2a, ya2b);
            *BsW1 = pack8(yb1a, yb1b);
            *BsW2 = pack8(yb2a, yb2b);
            asm volatile("s_waitcnt lgkmcnt(0)\n\ts_barrier" ::: "memory");
            if (k0 + 96 < 768) {
                ya1a = *(const float4*)(aG1 + k0 + 96); ya1b = *(const float4*)(aG1 + k0 + 100);
                ya2a = *(const float4*)(aG2 + k0 + 96); ya2b = *(const float4*)(aG2 + k0 + 100);
                yb1a = *(const float4*)(bG1 + k0 + 96); yb1b = *(const float4*)(bG1 + k0 + 100);
                yb2a = *(const float4*)(bG2 + k0 + 96); yb2b = *(const float4*)(bG2 + k0 + 100);
            }
            bf16x8 af[4], bfr[4];
#pragma unroll
            for (int i = 0; i < 4; ++i) af[i]  = *(const bf16x8*)&As[aoff[i]];
#pragma unroll
            for (int j = 0; j < 4; ++j) bfr[j] = *(const bf16x8*)&Bs[boff[j]];
#pragma unroll
            for (int i = 0; i < 4; ++i)
#pragma unroll
                for (int j = 0; j < 4; ++j)
                    acc[i][j] = __builtin_amdgcn_mfma_f32_16x16x32_bf16(af[i], bfr[j], acc[i][j], 0, 0, 0);
            asm volatile("s_barrier" ::: "memory");
        }
    }

#pragma unroll
    for (int i = 0; i < 4; ++i)
#pragma unroll
        for (int j = 0; j < 4; ++j)
#pragma unroll
            for (int r = 0; r < 4; ++r) {
                int row = m0 + wm + i * 16 + q * 4 + r;
                int col = n0 + wn + j * 16 + lr;
                if (!wd) web[(size_t)row * 768 + col] = (__bf16)acc[i][j][r];
                else     wdf[(size_t)row * 768 + col] = acc[i][j][r];
            }
}

// ---------------- scores: LDS-free, register-cached -----------------------------
// Block = (b, 16 contiguous l rows), 256 thr = 16 ls x 16 hc. Thread owns the 48
// h-elements {hc*8 + j*128 + e}, keeps we (unpacked bf16) and V in registers, and
// streams wd[t] (f32, L2-resident 786KB total) per t. Per-(wave,t) uniform skip
// of fully-masked t (l_max_in_wave < X[t]) ~48% of work. Reduction over hc = 4
// shfl_xor. No LDS, no __syncthreads. l0 reversed so heavy blocks dispatch first.
__global__ __launch_bounds__(256) void scores_k(
        const __bf16* __restrict__ web, const float* __restrict__ wdf,
        const float* __restrict__ V, const int* __restrict__ Xi,
        float* __restrict__ scores) {
    const int b  = blockIdx.x;
    const int l0 = ((int)gridDim.y - 1 - (int)blockIdx.y) * 16;   // heavy first
    const int tid = threadIdx.x;
    const int ls = tid >> 4, hc = tid & 15;
    const int l  = l0 + ls;
    const int h0 = hc * 8;

    float we[48], vv[48];
    const __bf16* wr = web + ((size_t)(b * L_ + l)) * H_ + h0;
#pragma unroll
    for (int j = 0; j < 6; ++j) {
        uint4 u = *(const uint4*)(wr + j * 128);
        we[j*8+0] = bf_lo(u.x); we[j*8+1] = bf_hi(u.x);
        we[j*8+2] = bf_lo(u.y); we[j*8+3] = bf_hi(u.y);
        we[j*8+4] = bf_lo(u.z); we[j*8+5] = bf_hi(u.z);
        we[j*8+6] = bf_lo(u.w); we[j*8+7] = bf_hi(u.w);
    }
    const float* vp = V + h0;
#pragma unroll
    for (int j = 0; j < 6; ++j) {
        float4 a = *(const float4*)(vp + j * 128);
        float4 c = *(const float4*)(vp + j * 128 + 4);
        vv[j*8+0] = a.x; vv[j*8+1] = a.y; vv[j*8+2] = a.z; vv[j*8+3] = a.w;
        vv[j*8+4] = c.x; vv[j*8+5] = c.y; vv[j*8+6] = c.z; vv[j*8+7] = c.w;
    }

    const int wmaxl = l0 + ((tid >> 6) << 2) + 3;   // wave covers ls = 4w..4w+3
    const int bT = b * T_;
#pragma unroll 1
    for (int t = 0; t < T_; ++t) {
        const int X = Xi[bT + t];
        if (wmaxl < X) continue;                    // wave-uniform masked skip
        const float* wdp = wdf + ((size_t)(bT + t)) * H_ + h0;
        float a0 = 0.f, a1 = 0.f, a2 = 0.f, a3 = 0.f;
#pragma unroll
        for (int j = 0; j < 6; ++j) {
            float4 x = *(const float4*)(wdp + j * 128);
            float4 y = *(const float4*)(wdp + j * 128 + 4);
            a0 = fmaf(selu_core(we[j*8+0] + x.x), vv[j*8+0], a0);
            a1 = fmaf(selu_core(we[j*8+1] + x.y), vv[j*8+1], a1);
            a2 = fmaf(selu_core(we[j*8+2] + x.z), vv[j*8+2], a2);
            a3 = fmaf(selu_core(we[j*8+3] + x.w), vv[j*8+3], a3);
            a0 = fmaf(selu_core(we[j*8+4] + y.x), vv[j*8+4], a0);
            a1 = fmaf(selu_core(we[j*8+5] + y.y), vv[j*8+5], a1);
            a2 = fmaf(selu_core(we[j*8+6] + y.z), vv[j*8+6], a2);
            a3 = fmaf(selu_core(we[j*8+7] + y.w), vv[j*8+7], a3);
        }
        float dot = (a0 + a1) + (a2 + a3);
        dot += __shfl_xor(dot, 1);
        dot += __shfl_xor(dot, 2);
        dot += __shfl_xor(dot, 4);
        dot += __shfl_xor(dot, 8);
        if (hc == 0) {
            dot *= SELU_SCALE;
            float sc = dot > 0.0f ? SELU_SCALE * dot
                                  : SELU_SCALE * SELU_ALPHA * (__expf(dot) - 1.0f);
            scores[((size_t)(bT + t)) * L_ + l] = sc;
        }
    }
}

// ---------------- per-(b,t) masked logsumexp + gold + mean (atomic) -------------
__global__ __launch_bounds__(64) void loss_k(
        const float* __restrict__ scores, const int* __restrict__ Xi,
        const int* __restrict__ Yi, float* __restrict__ out) {
    const int bt = blockIdx.x;
    const int lane = threadIdx.x;
    const int X = Xi[bt];
    const int Y = Yi[bt];
    const float* row = scores + (size_t)bt * L_;

    float m = -INFINITY;
    for (int l = X + lane; l < L_; l += 64) m = fmaxf(m, row[l]);
#pragma unroll
    for (int off = 32; off > 0; off >>= 1) m = fmaxf(m, __shfl_xor(m, off));

    float s = 0.0f;
    for (int l = X + lane; l < L_; l += 64) s += __expf(row[l] - m);
#pragma unroll
    for (int off = 32; off > 0; off >>= 1) s += __shfl_xor(s, off);

    if (lane == 0)
        atomicAdd(out, (m + __logf(s) - row[Y]) * (1.0f / (B_ * T_)));
}

// ---------------- launch ----------------
extern "C" void kernel_launch(void* const* d_in, const int* in_sizes, int n_in,
                              void* d_out, int out_size, void* d_ws, size_t ws_size,
                              hipStream_t stream) {
    const float* hn  = (const float*)d_in[0];
    const float* dec = (const float*)d_in[1];
    const float* W1  = (const float*)d_in[2];
    const float* W2  = (const float*)d_in[3];
    const float* V   = (const float*)d_in[4];
    const int*   Xi  = (const int*)d_in[5];
    const int*   Yi  = (const int*)d_in[6];
    float* out = (float*)d_out;

    char* ws = (char*)d_ws;
    size_t off = 0;
    auto alloc = [&](size_t bytes) -> char* {
        char* p = ws + off;
        off += (bytes + 255) & ~(size_t)255;
        return p;
    };
    __bf16* web    = (__bf16*)alloc((size_t)B_ * L_ * H_ * 2);
    float*  wdf    = (float*)alloc((size_t)B_ * T_ * H_ * 4);
    float*  scores = (float*)alloc((size_t)B_ * T_ * L_ * 4);

    // WE (384 blocks, XCD-swizzled) + WD (12 blocks, self-gathering dj)
    gemm_k<<<396, 256, 0, stream>>>(hn, dec, W1, W2, Yi, web, wdf, out);
    scores_k<<<dim3(B_, L_ / 16), 256, 0, stream>>>(web, wdf, V, Xi, scores);
    loss_k<<<B_ * T_, 64, 0, stream>>>(scores, Xi, Yi, out);
}

// Round 2
// 149.974 us; speedup vs baseline: 1.1116x; 1.1116x over previous
//
#include <hip/hip_runtime.h>
#include <hip/hip_bf16.h>
#include <math.h>

#define SELU_SCALE 1.0507009873554805f
#define SELU_ALPHA 1.6732632423543772f

static constexpr int B_ = 16, T_ = 16, L_ = 512, H_ = 768;

typedef __bf16 bf16x8 __attribute__((ext_vector_type(8)));
typedef float  f32x4  __attribute__((ext_vector_type(4)));

__device__ __forceinline__ float bf_lo(unsigned u) { return __uint_as_float(u << 16); }
__device__ __forceinline__ float bf_hi(unsigned u) { return __uint_as_float(u & 0xFFFF0000u); }

__device__ __forceinline__ float selu_core(float x) {
    float e = fmaf(__expf(x), SELU_ALPHA, -SELU_ALPHA);
    return x > 0.0f ? x : e;
}

// LDS k-segment slot swizzle: slot = seg ^ ((row>>1)&3). r6 measured 0 conflicts
// for these write/read patterns (16-row x 64B contiguous 1KB per wave-op).
__device__ __forceinline__ int xsw(int r) { return (r >> 1) & 3; }

__device__ __forceinline__ bf16x8 pack8(float4 a, float4 b) {
    bf16x8 o;
    o[0] = (__bf16)a.x; o[1] = (__bf16)a.y; o[2] = (__bf16)a.z; o[3] = (__bf16)a.w;
    o[4] = (__bf16)b.x; o[5] = (__bf16)b.y; o[6] = (__bf16)b.z; o[7] = (__bf16)b.w;
    return o;
}

// ---------------- fused NT GEMM (WE + WD), no prep pass -------------------------
// Unchanged from the 152µs session kernel except WD writes f32 (wdf). 128x128
// tile, 4 waves of 64x64 (4x4 MFMA 16x16x32), BK=32, prefetch distance ~2,
// statically named X/Y register sets, XCD-aware block mapping.
__global__ __launch_bounds__(256, 2) void gemm_k(
        const float* __restrict__ hn, const float* __restrict__ dec,
        const float* __restrict__ w1, const float* __restrict__ w2,
        const int* __restrict__ Yi,
        __bf16* __restrict__ web, float* __restrict__ wdf,
        float* __restrict__ out) {
    __shared__ __bf16 As[128 * 32];   // 8 KB
    __shared__ __bf16 Bs[128 * 32];   // 8 KB

    const int tid = threadIdx.x;
    if (blockIdx.x == 0 && tid == 0) out[0] = 0.0f;   // for loss_k atomics

    int bx = blockIdx.x;
    const float* Wf; int m0, n0; bool wd;
    if (bx < 384) {                      // WE: 64 m-tiles x 6 n-chunks
        wd = false; Wf = w1;
        m0 = (bx & 63) * 128; n0 = (bx >> 6) * 128;
    } else {                             // WD: 2 m-tiles x 6 n-chunks
        wd = true; bx -= 384; Wf = w2;
        m0 = (bx & 1) * 128;  n0 = (bx >> 1) * 128;
    }

    const int wave = tid >> 6, lane = tid & 63;
    const int wm = (wave >> 1) * 64, wn = (wave & 1) * 64;
    const int lr = lane & 15, q = lane >> 4;

    // staging: thread -> rows r1 = wave*32+(lane>>2), r2 = r1+16; slot s3 = lane&3
    // holds global k-seg g1 = s3 ^ xsw(r1)  (xsw(r1) == xsw(r1+16))
    const int r1 = wave * 32 + (lane >> 2);
    const int s3 = lane & 3;
    const int g1 = s3 ^ xsw(r1);

    const float *aG1, *aG2;
    if (!wd) {
        aG1 = hn + (size_t)(m0 + r1) * 768 + g1 * 8;
        aG2 = aG1 + (size_t)16 * 768;
    } else {
        int bt1 = m0 + r1, bt2 = bt1 + 16;
        aG1 = dec + ((size_t)((bt1 >> 4) * L_ + Yi[bt1])) * 768 + g1 * 8;
        aG2 = dec + ((size_t)((bt2 >> 4) * L_ + Yi[bt2])) * 768 + g1 * 8;
    }
    const float* bG1 = Wf + (size_t)(n0 + r1) * 768 + g1 * 8;
    const float* bG2 = bG1 + (size_t)16 * 768;

    bf16x8* AsW1 = (bf16x8*)&As[r1 * 32 + s3 * 8];
    bf16x8* AsW2 = (bf16x8*)&As[(r1 + 16) * 32 + s3 * 8];
    bf16x8* BsW1 = (bf16x8*)&Bs[r1 * 32 + s3 * 8];
    bf16x8* BsW2 = (bf16x8*)&Bs[(r1 + 16) * 32 + s3 * 8];

    // fragment read offsets (global seg q at slot q^xsw(row))
    int aoff[4], boff[4];
#pragma unroll
    for (int i = 0; i < 4; ++i) {
        int r = wm + i * 16 + lr;
        aoff[i] = r * 32 + (q ^ xsw(r)) * 8;
    }
#pragma unroll
    for (int j = 0; j < 4; ++j) {
        int r = wn + j * 16 + lr;
        boff[j] = r * 32 + (q ^ xsw(r)) * 8;
    }

    f32x4 acc[4][4] = {};

    // prologue: tile k=0 -> set X, tile k=32 -> set Y (statically named)
    float4 xa1a = *(const float4*)(aG1);      float4 xa1b = *(const float4*)(aG1 + 4);
    float4 xa2a = *(const float4*)(aG2);      float4 xa2b = *(const float4*)(aG2 + 4);
    float4 xb1a = *(const float4*)(bG1);      float4 xb1b = *(const float4*)(bG1 + 4);
    float4 xb2a = *(const float4*)(bG2);      float4 xb2b = *(const float4*)(bG2 + 4);
    float4 ya1a = *(const float4*)(aG1 + 32); float4 ya1b = *(const float4*)(aG1 + 36);
    float4 ya2a = *(const float4*)(aG2 + 32); float4 ya2b = *(const float4*)(aG2 + 36);
    float4 yb1a = *(const float4*)(bG1 + 32); float4 yb1b = *(const float4*)(bG1 + 36);
    float4 yb2a = *(const float4*)(bG2 + 32); float4 yb2b = *(const float4*)(bG2 + 36);

#pragma unroll 1
    for (int k0 = 0; k0 < 768; k0 += 64) {
        // ======== sub-iter X: tile k0 ========
        {
            *AsW1 = pack8(xa1a, xa1b);
            *AsW2 = pack8(xa2a, xa2b);
            *BsW1 = pack8(xb1a, xb1b);
            *BsW2 = pack8(xb2a, xb2b);
            asm volatile("s_waitcnt lgkmcnt(0)\n\ts_barrier" ::: "memory");
            if (k0 + 64 < 768) {
                xa1a = *(const float4*)(aG1 + k0 + 64); xa1b = *(const float4*)(aG1 + k0 + 68);
                xa2a = *(const float4*)(aG2 + k0 + 64); xa2b = *(const float4*)(aG2 + k0 + 68);
                xb1a = *(const float4*)(bG1 + k0 + 64); xb1b = *(const float4*)(bG1 + k0 + 68);
                xb2a = *(const float4*)(bG2 + k0 + 64); xb2b = *(const float4*)(bG2 + k0 + 68);
            }
            bf16x8 af[4], bfr[4];
#pragma unroll
            for (int i = 0; i < 4; ++i) af[i]  = *(const bf16x8*)&As[aoff[i]];
#pragma unroll
            for (int j = 0; j < 4; ++j) bfr[j] = *(const bf16x8*)&Bs[boff[j]];
#pragma unroll
            for (int i = 0; i < 4; ++i)
#pragma unroll
                for (int j = 0; j < 4; ++j)
                    acc[i][j] = __builtin_amdgcn_mfma_f32_16x16x32_bf16(af[i], bfr[j], acc[i][j], 0, 0, 0);
            asm volatile("s_barrier" ::: "memory");
        }
        // ======== sub-iter Y: tile k0+32 ========
        {
            *AsW1 = pack8(ya1a, ya1b);
            *AsW2 = pack8(ya2a, ya2b);
            *BsW1 = pack8(yb1a, yb1b);
            *BsW2 = pack8(yb2a, yb2b);
            asm volatile("s_waitcnt lgkmcnt(0)\n\ts_barrier" ::: "memory");
            if (k0 + 96 < 768) {
                ya1a = *(const float4*)(aG1 + k0 + 96); ya1b = *(const float4*)(aG1 + k0 + 100);
                ya2a = *(const float4*)(aG2 + k0 + 96); ya2b = *(const float4*)(aG2 + k0 + 100);
                yb1a = *(const float4*)(bG1 + k0 + 96); yb1b = *(const float4*)(bG1 + k0 + 100);
                yb2a = *(const float4*)(bG2 + k0 + 96); yb2b = *(const float4*)(bG2 + k0 + 100);
            }
            bf16x8 af[4], bfr[4];
#pragma unroll
            for (int i = 0; i < 4; ++i) af[i]  = *(const bf16x8*)&As[aoff[i]];
#pragma unroll
            for (int j = 0; j < 4; ++j) bfr[j] = *(const bf16x8*)&Bs[boff[j]];
#pragma unroll
            for (int i = 0; i < 4; ++i)
#pragma unroll
                for (int j = 0; j < 4; ++j)
                    acc[i][j] = __builtin_amdgcn_mfma_f32_16x16x32_bf16(af[i], bfr[j], acc[i][j], 0, 0, 0);
            asm volatile("s_barrier" ::: "memory");
        }
    }

#pragma unroll
    for (int i = 0; i < 4; ++i)
#pragma unroll
        for (int j = 0; j < 4; ++j)
#pragma unroll
            for (int r = 0; r < 4; ++r) {
                int row = m0 + wm + i * 16 + q * 4 + r;
                int col = n0 + wn + j * 16 + lr;
                if (!wd) web[(size_t)row * 768 + col] = (__bf16)acc[i][j][r];
                else     wdf[(size_t)row * 768 + col] = acc[i][j][r];
            }
}

// ---------------- scores: LDS-free, register-cached, t-split for occupancy ------
// Block = (b, 16 l rows, 4 t's). 256 thr = 16 ls x 16 hc. Thread owns the 48
// h-elements {hc*8 + j*128 + e}, keeps we (unpacked bf16) and V in registers,
// streams wd[t] (f32, L2-resident) per t. Grid = 16x32x4 = 2048 blocks ->
// 8 blocks/CU = 32 waves/CU (r1 fix: 512 blocks gave 8 waves/CU, VALUBusy 22%,
// latency-bound). Per-(wave,t) uniform skip of fully-masked t (~48%). Reduction
// over hc = 4 shfl_xor. No LDS, no __syncthreads. l0 reversed: heavy-first.
__global__ __launch_bounds__(256) void scores_k(
        const __bf16* __restrict__ web, const float* __restrict__ wdf,
        const float* __restrict__ V, const int* __restrict__ Xi,
        float* __restrict__ scores) {
    const int b  = blockIdx.x;
    const int l0 = ((int)gridDim.y - 1 - (int)blockIdx.y) * 16;   // heavy first
    const int t0 = blockIdx.z * 4;
    const int tid = threadIdx.x;
    const int ls = tid >> 4, hc = tid & 15;
    const int l  = l0 + ls;
    const int h0 = hc * 8;

    float we[48], vv[48];
    const __bf16* wr = web + ((size_t)(b * L_ + l)) * H_ + h0;
#pragma unroll
    for (int j = 0; j < 6; ++j) {
        uint4 u = *(const uint4*)(wr + j * 128);
        we[j*8+0] = bf_lo(u.x); we[j*8+1] = bf_hi(u.x);
        we[j*8+2] = bf_lo(u.y); we[j*8+3] = bf_hi(u.y);
        we[j*8+4] = bf_lo(u.z); we[j*8+5] = bf_hi(u.z);
        we[j*8+6] = bf_lo(u.w); we[j*8+7] = bf_hi(u.w);
    }
    const float* vp = V + h0;
#pragma unroll
    for (int j = 0; j < 6; ++j) {
        float4 a = *(const float4*)(vp + j * 128);
        float4 c = *(const float4*)(vp + j * 128 + 4);
        vv[j*8+0] = a.x; vv[j*8+1] = a.y; vv[j*8+2] = a.z; vv[j*8+3] = a.w;
        vv[j*8+4] = c.x; vv[j*8+5] = c.y; vv[j*8+6] = c.z; vv[j*8+7] = c.w;
    }

    const int wmaxl = l0 + ((tid >> 6) << 2) + 3;   // wave covers ls = 4w..4w+3
    const int bT = b * T_;
#pragma unroll 1
    for (int t = t0; t < t0 + 4; ++t) {
        const int X = Xi[bT + t];
        if (wmaxl < X) continue;                    // wave-uniform masked skip
        const float* wdp = wdf + ((size_t)(bT + t)) * H_ + h0;
        float a0 = 0.f, a1 = 0.f, a2 = 0.f, a3 = 0.f;
#pragma unroll
        for (int j = 0; j < 6; ++j) {
            float4 x = *(const float4*)(wdp + j * 128);
            float4 y = *(const float4*)(wdp + j * 128 + 4);
            a0 = fmaf(selu_core(we[j*8+0] + x.x), vv[j*8+0], a0);
            a1 = fmaf(selu_core(we[j*8+1] + x.y), vv[j*8+1], a1);
            a2 = fmaf(selu_core(we[j*8+2] + x.z), vv[j*8+2], a2);
            a3 = fmaf(selu_core(we[j*8+3] + x.w), vv[j*8+3], a3);
            a0 = fmaf(selu_core(we[j*8+4] + y.x), vv[j*8+4], a0);
            a1 = fmaf(selu_core(we[j*8+5] + y.y), vv[j*8+5], a1);
            a2 = fmaf(selu_core(we[j*8+6] + y.z), vv[j*8+6], a2);
            a3 = fmaf(selu_core(we[j*8+7] + y.w), vv[j*8+7], a3);
        }
        float dot = (a0 + a1) + (a2 + a3);
        dot += __shfl_xor(dot, 1);
        dot += __shfl_xor(dot, 2);
        dot += __shfl_xor(dot, 4);
        dot += __shfl_xor(dot, 8);
        if (hc == 0) {
            dot *= SELU_SCALE;
            float sc = dot > 0.0f ? SELU_SCALE * dot
                                  : SELU_SCALE * SELU_ALPHA * (__expf(dot) - 1.0f);
            scores[((size_t)(bT + t)) * L_ + l] = sc;
        }
    }
}

// ---------------- per-(b,t) masked logsumexp + gold + mean (atomic) -------------
__global__ __launch_bounds__(64) void loss_k(
        const float* __restrict__ scores, const int* __restrict__ Xi,
        const int* __restrict__ Yi, float* __restrict__ out) {
    const int bt = blockIdx.x;
    const int lane = threadIdx.x;
    const int X = Xi[bt];
    const int Y = Yi[bt];
    const float* row = scores + (size_t)bt * L_;

    float m = -INFINITY;
    for (int l = X + lane; l < L_; l += 64) m = fmaxf(m, row[l]);
#pragma unroll
    for (int off = 32; off > 0; off >>= 1) m = fmaxf(m, __shfl_xor(m, off));

    float s = 0.0f;
    for (int l = X + lane; l < L_; l += 64) s += __expf(row[l] - m);
#pragma unroll
    for (int off = 32; off > 0; off >>= 1) s += __shfl_xor(s, off);

    if (lane == 0)
        atomicAdd(out, (m + __logf(s) - row[Y]) * (1.0f / (B_ * T_)));
}

// ---------------- launch ----------------
extern "C" void kernel_launch(void* const* d_in, const int* in_sizes, int n_in,
                              void* d_out, int out_size, void* d_ws, size_t ws_size,
                              hipStream_t stream) {
    const float* hn  = (const float*)d_in[0];
    const float* dec = (const float*)d_in[1];
    const float* W1  = (const float*)d_in[2];
    const float* W2  = (const float*)d_in[3];
    const float* V   = (const float*)d_in[4];
    const int*   Xi  = (const int*)d_in[5];
    const int*   Yi  = (const int*)d_in[6];
    float* out = (float*)d_out;

    char* ws = (char*)d_ws;
    size_t off = 0;
    auto alloc = [&](size_t bytes) -> char* {
        char* p = ws + off;
        off += (bytes + 255) & ~(size_t)255;
        return p;
    };
    __bf16* web    = (__bf16*)alloc((size_t)B_ * L_ * H_ * 2);
    float*  wdf    = (float*)alloc((size_t)B_ * T_ * H_ * 4);
    float*  scores = (float*)alloc((size_t)B_ * T_ * L_ * 4);

    // WE (384 blocks, XCD-swizzled) + WD (12 blocks, self-gathering dj)
    gemm_k<<<396, 256, 0, stream>>>(hn, dec, W1, W2, Yi, web, wdf, out);
    scores_k<<<dim3(B_, L_ / 16, T_ / 4), 256, 0, stream>>>(web, wdf, V, Xi, scores);
    loss_k<<<B_ * T_, 64, 0, stream>>>(scores, Xi, Yi, out);
}